// Round 7
// baseline (374.255 us; speedup 1.0000x reference)
//
#include <hip/hip_runtime.h>

#define U_NODES 200000
#define B_ROWS  20000
#define K_S     33
#define F_DIM   256
#define E_DIM   128
#define NPART   128

typedef __bf16 bf16x8 __attribute__((ext_vector_type(8)));
typedef float  f32x4  __attribute__((ext_vector_type(4)));
typedef unsigned short ushortx8 __attribute__((ext_vector_type(8)));

__device__ __forceinline__ unsigned short f2bf(float f) {
    unsigned int u = __builtin_bit_cast(unsigned int, f);
    u += 0x7fffu + ((u >> 16) & 1u);            // round-to-nearest-even
    return (unsigned short)(u >> 16);
}
__device__ __forceinline__ float bf2f(unsigned short s) {
    return __builtin_bit_cast(float, ((unsigned int)s) << 16);
}

// ---------------------------------------------------------------------------
// One-time prep: Wt[n][k] = bf16(W[k][n]) so B-fragments are contiguous-k.
// ---------------------------------------------------------------------------
__global__ void wprep_kernel(const float* __restrict__ W, unsigned short* __restrict__ Wt) {
    int n = blockIdx.x;      // 128
    int k = threadIdx.x;     // 256
    Wt[n * F_DIM + k] = f2bf(W[(size_t)k * E_DIM + n]);
}

// ---------------------------------------------------------------------------
// Pass X — DISCRIMINATING EXPERIMENT (R6 post-mortem): pure m13-copy-style
// grid-stride cast Abf = bf16(A). This is the ONLY structure measured at
// 6.29 TB/s on this chip. If it runs at copy speed, the gemm plateau was a
// kernel-structure defect; if it runs at ~2 TB/s, the plateau is
// environmental (harness traffic sharing the window) and we're at the floor.
// ---------------------------------------------------------------------------
__global__ __launch_bounds__(256) void cast_kernel(
    const float* __restrict__ A, unsigned short* __restrict__ Abf)
{
    const long long NCH = (long long)U_NODES * F_DIM / 8;   // 6.4M ushort8 chunks
    for (long long c = blockIdx.x * 256LL + threadIdx.x; c < NCH; c += gridDim.x * 256LL) {
        const float* p = A + c * 8;
        float4 v0 = *(const float4*)(p);
        float4 v1 = *(const float4*)(p + 4);
        ushortx8 u = { f2bf(v0.x), f2bf(v0.y), f2bf(v0.z), f2bf(v0.w),
                       f2bf(v1.x), f2bf(v1.y), f2bf(v1.z), f2bf(v1.w) };
        *(ushortx8*)(Abf + c * 8) = u;
    }
}

// ---------------------------------------------------------------------------
// Pass Y — MFMA gemm from bf16 A: each thread's 8 upfront dwordx4 loads ARE
// the MFMA A-fragments (no cvt, no staging, no transpose). W staged in two
// 32KB LDS halves (XOR-swizzled, <=2-way). Fused BN stats via NPART partials.
// ---------------------------------------------------------------------------
__global__ __launch_bounds__(256) void gemm_stats_kernel(
    const unsigned short* __restrict__ Abf, const unsigned short* __restrict__ Wt,
    unsigned short* __restrict__ h, float* __restrict__ part)
{
    __shared__ __attribute__((aligned(16))) char smem[32768];  // W half: [128 n][128 k] bf16

    const int t    = threadIdx.x;
    const int lane = t & 63;
    const int wv   = t >> 6;
    const int m    = lane & 15;
    const int qd   = lane >> 4;
    const int row0 = blockIdx.x * 64;
    const int row  = row0 + wv * 16 + m;           // exact: 3125*64 == 200000

    // ---- 8 upfront A-loads = the 8 k-fragments for this lane's row ----
    const unsigned short* Ap = Abf + (size_t)row * F_DIM + qd * 8;
    bf16x8 af[8];
    #pragma unroll
    for (int kf = 0; kf < 8; ++kf)
        af[kf] = __builtin_bit_cast(bf16x8, *(const ushortx8*)(Ap + kf * 32));

    // ---- stage W half 0 ----
    #pragma unroll
    for (int i = 0; i < 8; ++i) {
        int of = t + 256 * i, n = of >> 4, o = of & 15;
        ushortx8 v = *(const ushortx8*)(Wt + n * F_DIM + o * 8);
        *(ushortx8*)(smem + n * 256 + (((o & 8) | ((o ^ n) & 7)) << 4)) = v;
    }

    f32x4 acc[8];
    #pragma unroll
    for (int ct = 0; ct < 8; ++ct) acc[ct] = (f32x4){0.f, 0.f, 0.f, 0.f};

    __syncthreads();
    // ---- compute half 0 (kf 0..3) ----
    #pragma unroll
    for (int kfl = 0; kfl < 4; ++kfl) {
        int o = kfl * 4 + qd;
        #pragma unroll
        for (int ct = 0; ct < 8; ++ct) {
            int n = ct * 16 + m;
            bf16x8 b = *(const bf16x8*)(smem + n * 256 + (((o & 8) | ((o ^ n) & 7)) << 4));
            acc[ct] = __builtin_amdgcn_mfma_f32_16x16x32_bf16(af[kfl], b, acc[ct], 0, 0, 0);
        }
    }
    // ---- stage W half 1 ----
    ushortx8 wreg[8];
    #pragma unroll
    for (int i = 0; i < 8; ++i) {
        int of = t + 256 * i, n = of >> 4, o = of & 15;
        wreg[i] = *(const ushortx8*)(Wt + n * F_DIM + 128 + o * 8);
    }
    __syncthreads();
    #pragma unroll
    for (int i = 0; i < 8; ++i) {
        int of = t + 256 * i, n = of >> 4, o = of & 15;
        *(ushortx8*)(smem + n * 256 + (((o & 8) | ((o ^ n) & 7)) << 4)) = wreg[i];
    }
    __syncthreads();
    // ---- compute half 1 (kf 4..7) ----
    #pragma unroll
    for (int kfl = 0; kfl < 4; ++kfl) {
        int o = kfl * 4 + qd;
        #pragma unroll
        for (int ct = 0; ct < 8; ++ct) {
            int n = ct * 16 + m;
            bf16x8 b = *(const bf16x8*)(smem + n * 256 + (((o & 8) | ((o ^ n) & 7)) << 4));
            acc[ct] = __builtin_amdgcn_mfma_f32_16x16x32_bf16(af[4 + kfl], b, acc[ct], 0, 0, 0);
        }
    }
    __syncthreads();   // LDS reads done; reuse as reduction buffer

    // ---- BN stats (D layout m89: col = ct*16+m, row-in-tile = qd*4+v) ----
    float* red = (float*)smem;          // [16 rq][256]: cols 0..127 sum, 128..255 sumsq
    int rq = wv * 4 + qd;
    #pragma unroll
    for (int ct = 0; ct < 8; ++ct) {
        float ss = 0.f, qq = 0.f;
        #pragma unroll
        for (int v = 0; v < 4; ++v) { float x = acc[ct][v]; ss += x; qq += x * x; }
        red[rq * 256 + ct * 16 + m]       = ss;
        red[rq * 256 + 128 + ct * 16 + m] = qq;
    }
    __syncthreads();
    {
        float tot = 0.f;
        #pragma unroll
        for (int i = 0; i < 16; ++i) tot += red[i * 256 + t];
        atomicAdd(&part[(blockIdx.x & (NPART - 1)) * 256 + t], tot);
    }
    __syncthreads();

    // ---- h store: acc -> per-wave LDS transpose -> coalesced bf16x8 stores ----
    unsigned short* tb = (unsigned short*)(smem + wv * 4096);   // [16][128] per wave
    #pragma unroll
    for (int ct = 0; ct < 8; ++ct)
        #pragma unroll
        for (int v = 0; v < 4; ++v)
            tb[(qd * 4 + v) * 128 + ct * 16 + m] = f2bf(acc[ct][v]);
    __syncthreads();
    #pragma unroll
    for (int i = 0; i < 4; ++i) {
        int idx = lane + 64 * i;            // 0..255
        int r = idx >> 4, c8 = (idx & 15) * 8;
        int gr = row0 + wv * 16 + r;
        *(ushortx8*)(h + (size_t)gr * E_DIM + c8) = *(const ushortx8*)(tb + r * 128 + c8);
    }
}

// ---------------------------------------------------------------------------
// Reduce stat partials; fold BN stats + gamma/beta into scale/shift.
// ---------------------------------------------------------------------------
__global__ void finalize_kernel(const float* __restrict__ part,
                                const float* __restrict__ gamma, const float* __restrict__ beta,
                                float* __restrict__ scale, float* __restrict__ shift)
{
    int e = threadIdx.x;        // 0..127
    float sum = 0.f, sq = 0.f;
    for (int p = 0; p < NPART; ++p) {
        sum += part[p * 256 + e];
        sq  += part[p * 256 + 128 + e];
    }
    float mu  = sum * (1.f / U_NODES);
    float var = sq * (1.f / U_NODES) - mu * mu;
    float inv = rsqrtf(var + 1e-5f);
    float sc  = gamma[e] * inv;
    scale[e] = sc;
    shift[e] = beta[e] - sc * mu;
}

// ---------------------------------------------------------------------------
// Gather + BN + tanh + mean over K=33 (unchanged from R6: uint2/lane,
// 8 rows per 256-thr block, ~43us and structure-invariant).
// ---------------------------------------------------------------------------
__global__ __launch_bounds__(256, 4) void gather_kernel(
    const unsigned short* __restrict__ h, const int* __restrict__ sidx_g,
    const float* __restrict__ scale, const float* __restrict__ shift,
    float* __restrict__ out)
{
    __shared__ int sl[8 * K_S];
    const int t    = threadIdx.x;
    const int lane = t & 63;
    const int wv   = t >> 6;
    const int sub  = lane >> 5;         // half-wave -> row select
    const int e    = lane & 31;         // col group: cols e*4 .. e*4+3
    const int rloc = wv * 2 + sub;      // 0..7
    const int b0   = blockIdx.x * 8;
    for (int i = t; i < 8 * K_S; i += 256) sl[i] = sidx_g[(size_t)b0 * K_S + i];
    float scv[4], shv[4];
    *(float4*)scv = *(const float4*)(scale + e * 4);
    *(float4*)shv = *(const float4*)(shift + e * 4);
    __syncthreads();

    float acc[4] = {0.f, 0.f, 0.f, 0.f};
    #pragma unroll
    for (int k = 0; k < K_S; ++k) {
        int idx = sl[rloc * K_S + k];
        uint2 v = *(const uint2*)(h + (size_t)idx * E_DIM + e * 4);
        unsigned short c[4] = { (unsigned short)(v.x & 0xffff), (unsigned short)(v.x >> 16),
                                (unsigned short)(v.y & 0xffff), (unsigned short)(v.y >> 16) };
        #pragma unroll
        for (int j = 0; j < 4; ++j) {
            float x = bf2f(c[j]) * scv[j] + shv[j];
            acc[j] += 1.f - 2.f * __builtin_amdgcn_rcpf(__expf(2.f * x) + 1.f);  // tanh
        }
    }
    *(float4*)(out + (size_t)(b0 + rloc) * E_DIM + e * 4) =
        make_float4(acc[0] * (1.f / K_S), acc[1] * (1.f / K_S),
                    acc[2] * (1.f / K_S), acc[3] * (1.f / K_S));
}

// ---------------------------------------------------------------------------
extern "C" void kernel_launch(void* const* d_in, const int* in_sizes, int n_in,
                              void* d_out, int out_size, void* d_ws, size_t ws_size,
                              hipStream_t stream) {
    const float* features = (const float*)d_in[0];
    const float* W        = (const float*)d_in[1];
    // d_in[2] = bias — provably cancels inside BatchNorm; unused.
    const float* gamma    = (const float*)d_in[3];
    const float* beta     = (const float*)d_in[4];
    const int*   sample   = (const int*)d_in[5];
    float* out = (float*)d_out;

    // ws: part[128][256] | scale[128] shift[128] | Wt 64KB | Abf[U*256 bf16] | h[U*128 bf16]
    float* part  = (float*)d_ws;
    float* scale = part + NPART * 256;
    float* shift = scale + 128;
    unsigned short* Wt  = (unsigned short*)(shift + 128);
    unsigned short* Abf = Wt + 128 * 256;
    unsigned short* h   = Abf + (size_t)U_NODES * F_DIM;

    hipMemsetAsync(part, 0, NPART * 256 * sizeof(float), stream);
    wprep_kernel<<<128, 256, 0, stream>>>(W, Wt);
    cast_kernel<<<4096, 256, 0, stream>>>(features, Abf);
    gemm_stats_kernel<<<U_NODES / 64, 256, 0, stream>>>(Abf, Wt, h, part);
    finalize_kernel<<<1, 128, 0, stream>>>(part, gamma, beta, scale, shift);
    gather_kernel<<<B_ROWS / 8, 256, 0, stream>>>(h, sample, scale, shift, out);
}